// Round 1
// baseline (301.538 us; speedup 1.0000x reference)
//
#include <hip/hip_runtime.h>

typedef unsigned short u16;
typedef unsigned int u32;
typedef __attribute__((ext_vector_type(8))) __bf16 bf16x8;
typedef __attribute__((ext_vector_type(4))) float f32x4;
typedef __attribute__((ext_vector_type(4))) u32 u32x4;

#define DEV __device__ __forceinline__

constexpr int S_LEN = 2048;
constexpr int DMODEL = 1024;
constexpr int NHEAD = 16;
constexpr int EX = 3072;     // 3*D
constexpr int ROWS = 4096;   // B*S

DEV u16 f2bf(float f) {
  union { float f; u32 u; } v; v.f = f;
  u32 u = v.u;
  u32 r = (u + 0x7fffu + ((u >> 16) & 1u)) >> 16;  // RNE
  return (u16)r;
}
DEV float bf2f(u32 lo16) {
  union { u32 u; float f; } v; v.u = lo16 << 16; return v.f;
}

// ---------------- fp32 -> bf16 bulk convert (8 elems/thread) ----------------
__global__ __launch_bounds__(256) void k_f32_to_bf16(const float* __restrict__ in,
                                                     u16* __restrict__ out, int n8) {
  int i = blockIdx.x * 256 + threadIdx.x;
  if (i >= n8) return;
  const float4* p4 = (const float4*)in;
  float4 a = p4[2 * i], b = p4[2 * i + 1];
  alignas(16) u16 r[8] = {f2bf(a.x), f2bf(a.y), f2bf(a.z), f2bf(a.w),
                          f2bf(b.x), f2bf(b.y), f2bf(b.z), f2bf(b.w)};
  *(u32x4*)(out + 8 * i) = *(const u32x4*)r;
}

// ---------------- RoPE cos/sin tables: [S][32] ----------------
__global__ __launch_bounds__(256) void k_rope_tab(const int* __restrict__ pos,
                                                  float* __restrict__ ctab,
                                                  float* __restrict__ stab) {
  int t = blockIdx.x * 256 + threadIdx.x;  // S*32 = 65536
  int s = t >> 5, fi = t & 31;
  float p = (float)pos[s];
  // inv_freq = 10000^(-fi/32) = exp(-fi * ln(10000)/32)
  float invf = expf(-(float)fi * 0.28782313662425572f);
  float ang = p * invf;
  ctab[t] = cosf(ang);
  stab[t] = sinf(ang);
}

// ---------------- in-place RoPE on q,k thirds of qkv (bf16) ----------------
__global__ __launch_bounds__(256) void k_rope(u16* __restrict__ qkv,
                                              const float* __restrict__ ctab,
                                              const float* __restrict__ stab) {
  int idx = blockIdx.x * 256 + threadIdx.x;  // ROWS * 1024 pair-slots
  int row = idx >> 10, rem = idx & 1023;
  int p = rem >> 9, hfi = rem & 511;
  int h = hfi >> 5, fi = hfi & 31;
  int s = row & (S_LEN - 1);
  u32* ptr = (u32*)(qkv + (size_t)row * EX + p * 1024 + h * 64 + 2 * fi);
  u32 v = *ptr;
  float xe = bf2f(v & 0xffffu), xo = bf2f(v >> 16);
  float c = ctab[s * 32 + fi], sn = stab[s * 32 + fi];
  u32 lo = (u32)f2bf(xe * c - xo * sn);
  u32 hi = (u32)f2bf(xe * sn + xo * c);
  *ptr = lo | (hi << 16);
}

// ---------------- GEMM: C[m][n] = sum_k A[m][k] * B[n][k]  (both bf16, B^T layout)
// 128x128 tile, BK=32, 256 threads = 4 waves in 2x2, each wave 64x64 (4x4 MFMA frags)
template <int OUT_BF16>
__global__ __launch_bounds__(256) void k_gemm_bt(const u16* __restrict__ A,
                                                 const u16* __restrict__ Bw,
                                                 void* __restrict__ Out,
                                                 int M, int N, int K) {
  constexpr int LDP = 40;  // 32 + 8 pad: 80B row stride -> worst 2-way bank alias (free)
  __shared__ u16 As[128][LDP];
  __shared__ u16 Bs[128][LDP];
  const int tid = threadIdx.x;
  const int lane = tid & 63;
  const int w = tid >> 6, wr = w >> 1, wc = w & 1;
  const int l15 = lane & 15, l16 = lane >> 4;
  const int m0 = blockIdx.x * 128, n0 = blockIdx.y * 128;
  f32x4 acc[4][4] = {};
  const int srow = tid >> 2, scol = (tid & 3) * 8;  // 64 rows x 4 col-groups per round

  for (int k0 = 0; k0 < K; k0 += 32) {
    __syncthreads();
#pragma unroll
    for (int i = 0; i < 2; i++) {
      int row = i * 64 + srow;
      *(u32x4*)&As[row][scol] = *(const u32x4*)&A[(size_t)(m0 + row) * K + k0 + scol];
      *(u32x4*)&Bs[row][scol] = *(const u32x4*)&Bw[(size_t)(n0 + row) * K + k0 + scol];
    }
    __syncthreads();
    bf16x8 af[4], bf[4];
#pragma unroll
    for (int m = 0; m < 4; m++) af[m] = *(const bf16x8*)&As[wr * 64 + m * 16 + l15][l16 * 8];
#pragma unroll
    for (int n = 0; n < 4; n++) bf[n] = *(const bf16x8*)&Bs[wc * 64 + n * 16 + l15][l16 * 8];
#pragma unroll
    for (int m = 0; m < 4; m++)
#pragma unroll
      for (int n = 0; n < 4; n++)
        acc[m][n] = __builtin_amdgcn_mfma_f32_16x16x32_bf16(af[m], bf[n], acc[m][n], 0, 0, 0);
  }

  // C/D layout (m89/m91 verified): col = lane&15, row = (lane>>4)*4 + reg
  const int rb = m0 + wr * 64 + l16 * 4;
  const int cb = n0 + wc * 64 + l15;
#pragma unroll
  for (int m = 0; m < 4; m++)
#pragma unroll
    for (int n = 0; n < 4; n++)
#pragma unroll
      for (int r = 0; r < 4; r++) {
        int row = rb + m * 16 + r, col = cb + n * 16;
        if (OUT_BF16)
          ((u16*)Out)[(size_t)row * N + col] = f2bf(acc[m][n][r]);
        else
          ((float*)Out)[(size_t)row * N + col] = acc[m][n][r];
      }
}

// ---------------- causal flash attention ----------------
// grid: (S/64, B*H). block 256 = 4 waves; wave w owns q rows [q0+16w, q0+16w+16)
__global__ __launch_bounds__(256) void k_attn(const u16* __restrict__ qkv,
                                              u16* __restrict__ aout) {
  __shared__ u16 Ks[32][72];      // K tile, row-major kv x d, padded
  __shared__ u16 Vt[64][40];      // V^T tile, d x kv, padded
  __shared__ u16 Ps[4][16][40];   // per-wave P tile, q x kv, padded
  const int tid = threadIdx.x, lane = tid & 63, w = tid >> 6;
  const int l15 = lane & 15, l16 = lane >> 4;
  const int q0 = blockIdx.x * 64;
  const int bh = blockIdx.y, b = bh >> 4, h = bh & 15;
  const u16* base = qkv + (size_t)b * S_LEN * EX + h * 64;  // Q at +0, K at +1024, V at +2048
  const int wq0 = q0 + w * 16;

  bf16x8 qa[2];
#pragma unroll
  for (int kb = 0; kb < 2; kb++)
    qa[kb] = *(const bf16x8*)&base[(size_t)(wq0 + l15) * EX + kb * 32 + l16 * 8];

  f32x4 osum[4] = {};
  float mrow[4], lrow[4];
#pragma unroll
  for (int r = 0; r < 4; r++) { mrow[r] = -1e30f; lrow[r] = 0.f; }

  const int kv_end = q0 + 64;
  const int skv = tid >> 3, sd = (tid & 7) * 8;

  for (int kv0 = 0; kv0 < kv_end; kv0 += 32) {
    __syncthreads();
    {
      const u16* krow = base + 1024 + (size_t)(kv0 + skv) * EX;
      *(u32x4*)&Ks[skv][sd] = *(const u32x4*)&krow[sd];
      u32x4 vv = *(const u32x4*)&krow[1024 + sd];  // V row
      const u16* vp = (const u16*)&vv;
#pragma unroll
      for (int j = 0; j < 8; j++) Vt[sd + j][skv] = vp[j];
    }
    __syncthreads();

    if (kv0 <= wq0 + 15) {  // wave has at least one unmasked column in this tile
      f32x4 sc[2];
#pragma unroll
      for (int ct = 0; ct < 2; ct++) {
        bf16x8 kf0 = *(const bf16x8*)&Ks[ct * 16 + l15][l16 * 8];
        bf16x8 kf1 = *(const bf16x8*)&Ks[ct * 16 + l15][32 + l16 * 8];
        f32x4 z = {0.f, 0.f, 0.f, 0.f};
        f32x4 t0 = __builtin_amdgcn_mfma_f32_16x16x32_bf16(qa[0], kf0, z, 0, 0, 0);
        sc[ct] = __builtin_amdgcn_mfma_f32_16x16x32_bf16(qa[1], kf1, t0, 0, 0, 0);
      }
#pragma unroll
      for (int r = 0; r < 4; r++) {
        const int qrow = wq0 + l16 * 4 + r;
#pragma unroll
        for (int ct = 0; ct < 2; ct++) {
          int col = kv0 + ct * 16 + l15;
          sc[ct][r] = (col <= qrow) ? sc[ct][r] * 0.125f : -1e30f;
        }
        float t = fmaxf(sc[0][r], sc[1][r]);
        t = fmaxf(t, __shfl_xor(t, 1));
        t = fmaxf(t, __shfl_xor(t, 2));
        t = fmaxf(t, __shfl_xor(t, 4));
        t = fmaxf(t, __shfl_xor(t, 8));
        float mnew = fmaxf(mrow[r], t);
        float alpha = __expf(mrow[r] - mnew);
        mrow[r] = mnew;
        float p0 = __expf(sc[0][r] - mnew);
        float p1 = __expf(sc[1][r] - mnew);
        Ps[w][l16 * 4 + r][l15] = f2bf(p0);
        Ps[w][l16 * 4 + r][16 + l15] = f2bf(p1);
        float rs = p0 + p1;
        rs += __shfl_xor(rs, 1);
        rs += __shfl_xor(rs, 2);
        rs += __shfl_xor(rs, 4);
        rs += __shfl_xor(rs, 8);
        lrow[r] = lrow[r] * alpha + rs;
#pragma unroll
        for (int n = 0; n < 4; n++) osum[n][r] *= alpha;
      }
      // PV: A = P (16q x 32kv), B = V^T
      bf16x8 pa = *(const bf16x8*)&Ps[w][l15][l16 * 8];
#pragma unroll
      for (int n = 0; n < 4; n++) {
        bf16x8 vb = *(const bf16x8*)&Vt[n * 16 + l15][l16 * 8];
        osum[n] = __builtin_amdgcn_mfma_f32_16x16x32_bf16(pa, vb, osum[n], 0, 0, 0);
      }
    }
  }

#pragma unroll
  for (int r = 0; r < 4; r++) lrow[r] = 1.f / lrow[r];
  u16* ob = aout + (size_t)b * S_LEN * DMODEL + h * 64;
#pragma unroll
  for (int n = 0; n < 4; n++)
#pragma unroll
    for (int r = 0; r < 4; r++) {
      int s = wq0 + l16 * 4 + r;
      ob[(size_t)s * DMODEL + n * 16 + l15] = f2bf(osum[n][r] * lrow[r]);
    }
}

extern "C" void kernel_launch(void* const* d_in, const int* in_sizes, int n_in,
                              void* d_out, int out_size, void* d_ws, size_t ws_size,
                              hipStream_t stream) {
  const float* x = (const float*)d_in[0];
  const int* pos = (const int*)d_in[1];
  const float* wqkv = (const float*)d_in[2];
  const float* wout = (const float*)d_in[3];
  float* out = (float*)d_out;
  char* ws = (char*)d_ws;

  // workspace layout (bytes)
  u16* qkv  = (u16*)(ws);                       // 4096*3072*2 = 25,165,824
  u16* aoutb = (u16*)(ws + 25165824);           // 4096*1024*2 =  8,388,608
  u16* xb   = (u16*)(ws + 33554432);            // 4096*1024*2 =  8,388,608
  u16* wqb  = (u16*)(ws + 41943040);            // 3072*1024*2 =  6,291,456
  u16* wob  = (u16*)(ws + 48234496);            // 1024*1024*2 =  2,097,152
  float* ctab = (float*)(ws + 50331648);        // 2048*32*4   =    262,144
  float* stab = (float*)(ws + 50593792);        //                  262,144
  (void)ws_size;                                 // needs ~50.9 MB

  k_f32_to_bf16<<<(4194304 / 8) / 256, 256, 0, stream>>>(x, xb, 4194304 / 8);
  k_f32_to_bf16<<<(3145728 / 8) / 256, 256, 0, stream>>>(wqkv, wqb, 3145728 / 8);
  k_f32_to_bf16<<<(1048576 / 8) / 256, 256, 0, stream>>>(wout, wob, 1048576 / 8);
  k_rope_tab<<<65536 / 256, 256, 0, stream>>>(pos, ctab, stab);

  dim3 g1(ROWS / 128, EX / 128);  // 32 x 24
  k_gemm_bt<1><<<g1, 256, 0, stream>>>(xb, wqb, qkv, ROWS, EX, DMODEL);

  k_rope<<<(ROWS * 1024) / 256, 256, 0, stream>>>(qkv, ctab, stab);

  dim3 ga(S_LEN / 64, 2 * NHEAD);  // 32 x 32
  k_attn<<<ga, 256, 0, stream>>>(qkv, aoutb);

  dim3 g2(ROWS / 128, DMODEL / 128);  // 32 x 8
  k_gemm_bt<0><<<g2, 256, 0, stream>>>(aoutb, wob, out, ROWS, DMODEL, DMODEL);
}

// Round 2
// 158.643 us; speedup vs baseline: 1.9007x; 1.9007x over previous
//
#include <hip/hip_runtime.h>

typedef unsigned short u16;
typedef unsigned int u32;
typedef __attribute__((ext_vector_type(8))) __bf16 bf16x8;
typedef __attribute__((ext_vector_type(4))) float f32x4;
typedef __attribute__((ext_vector_type(4))) u32 u32x4;
typedef __attribute__((ext_vector_type(4))) u16 u16x4;

#define DEV __device__ __forceinline__

constexpr int S_LEN = 2048;
constexpr int DMODEL = 1024;
constexpr int NHEAD = 16;
constexpr int EX = 3072;     // 3*D
constexpr int ROWS = 4096;   // B*S

DEV u16 f2bf(float f) {
  union { float f; u32 u; } v; v.f = f;
  u32 u = v.u;
  u32 r = (u + 0x7fffu + ((u >> 16) & 1u)) >> 16;  // RNE
  return (u16)r;
}
DEV float bf2f(u32 lo16) {
  union { u32 u; float f; } v; v.u = lo16 << 16; return v.f;
}
// XOR swizzle for [rows][64] u16 LDS tiles (row stride 128B): spreads the
// 16-rows-same-col ds_read_b128 pattern across 8 bank-quads (G4 / T2).
DEV int swz(int r, int c) { return r * 64 + (c ^ ((r & 7) << 3)); }

// ---------------- fp32 -> bf16 bulk convert (8 elems/thread) ----------------
__global__ __launch_bounds__(256) void k_f32_to_bf16(const float* __restrict__ in,
                                                     u16* __restrict__ out, int n8) {
  int i = blockIdx.x * 256 + threadIdx.x;
  if (i >= n8) return;
  const float4* p4 = (const float4*)in;
  float4 a = p4[2 * i], b = p4[2 * i + 1];
  alignas(16) u16 r[8] = {f2bf(a.x), f2bf(a.y), f2bf(a.z), f2bf(a.w),
                          f2bf(b.x), f2bf(b.y), f2bf(b.z), f2bf(b.w)};
  *(u32x4*)(out + 8 * i) = *(const u32x4*)r;
}

// ---------------- RoPE cos/sin tables: [S][32] ----------------
__global__ __launch_bounds__(256) void k_rope_tab(const int* __restrict__ pos,
                                                  float* __restrict__ ctab,
                                                  float* __restrict__ stab) {
  int t = blockIdx.x * 256 + threadIdx.x;  // S*32 = 65536
  int s = t >> 5, fi = t & 31;
  float p = (float)pos[s];
  float invf = expf(-(float)fi * 0.28782313662425572f);  // 10000^(-fi/32)
  float ang = p * invf;
  ctab[t] = cosf(ang);
  stab[t] = sinf(ang);
}

// ---------------- in-place RoPE on qk buffer [ROWS][2048] (bf16) ----------------
__global__ __launch_bounds__(256) void k_rope(u16* __restrict__ qk,
                                              const float* __restrict__ ctab,
                                              const float* __restrict__ stab) {
  int idx = blockIdx.x * 256 + threadIdx.x;  // ROWS * 1024 pair-slots
  int row = idx >> 10, rem = idx & 1023;
  int p = rem >> 9, hfi = rem & 511;
  int h = hfi >> 5, fi = hfi & 31;
  int s = row & (S_LEN - 1);
  u32* ptr = (u32*)(qk + (size_t)row * 2048 + p * 1024 + h * 64 + 2 * fi);
  u32 v = *ptr;
  float xe = bf2f(v & 0xffffu), xo = bf2f(v >> 16);
  float c = ctab[s * 32 + fi], sn = stab[s * 32 + fi];
  u32 lo = (u32)f2bf(xe * c - xo * sn);
  u32 hi = (u32)f2bf(xe * sn + xo * c);
  *ptr = lo | (hi << 16);
}

// ---------------- GEMM: C[m][n] = sum_k A[m][k] * B[n][k]  (bf16, B^T layout)
// 128x128 tile, BK=32, 4 waves 2x2, wave 64x64 (4x4 MFMA frags).
// MODE 0: fp32 out [M][N].  MODE 1: qkv split — cols<2048 -> bf16 qk[row][2048];
// cols>=2048 (the V third) -> transposed bf16 vt[(b*16+h)*64+d][s].
template <int MODE>
__global__ __launch_bounds__(256) void k_gemm_bt(const u16* __restrict__ A,
                                                 const u16* __restrict__ Bw,
                                                 void* __restrict__ Out,
                                                 u16* __restrict__ vt,
                                                 int M, int N, int K) {
  constexpr int LDP = 40;  // 32+8 pad: 80B stride -> worst 2-way alias (free, m136)
  __shared__ u16 As[128][LDP];
  __shared__ u16 Bs[128][LDP];
  const int tid = threadIdx.x;
  const int lane = tid & 63;
  const int w = tid >> 6, wr = w >> 1, wc = w & 1;
  const int l15 = lane & 15, l16 = lane >> 4;
  const int m0 = blockIdx.x * 128, n0 = blockIdx.y * 128;
  f32x4 acc[4][4] = {};
  const int srow = tid >> 2, scol = (tid & 3) * 8;

  for (int k0 = 0; k0 < K; k0 += 32) {
    __syncthreads();
#pragma unroll
    for (int i = 0; i < 2; i++) {
      int row = i * 64 + srow;
      *(u32x4*)&As[row][scol] = *(const u32x4*)&A[(size_t)(m0 + row) * K + k0 + scol];
      *(u32x4*)&Bs[row][scol] = *(const u32x4*)&Bw[(size_t)(n0 + row) * K + k0 + scol];
    }
    __syncthreads();
    bf16x8 af[4], bfr[4];
#pragma unroll
    for (int m = 0; m < 4; m++) af[m] = *(const bf16x8*)&As[wr * 64 + m * 16 + l15][l16 * 8];
#pragma unroll
    for (int n = 0; n < 4; n++) bfr[n] = *(const bf16x8*)&Bs[wc * 64 + n * 16 + l15][l16 * 8];
#pragma unroll
    for (int m = 0; m < 4; m++)
#pragma unroll
      for (int n = 0; n < 4; n++)
        acc[m][n] = __builtin_amdgcn_mfma_f32_16x16x32_bf16(af[m], bfr[n], acc[m][n], 0, 0, 0);
  }

  // C/D layout (m89/m91): col = lane&15, row = (lane>>4)*4 + reg
  const int rb = m0 + wr * 64 + l16 * 4;
  const int cb = n0 + wc * 64 + l15;
  if (MODE == 1 && n0 >= 2048) {
    // V third -> vt[(b*1024 + hd)][s], 4 consecutive s per lane packed as 8B
#pragma unroll
    for (int m = 0; m < 4; m++)
#pragma unroll
      for (int n = 0; n < 4; n++) {
        int row = rb + m * 16;            // 4 consecutive rows r=0..3
        int col = cb + n * 16;
        int bb = row >> 11, s = row & 2047, hd = col - 2048;
        u16x4 pk = {f2bf(acc[m][n][0]), f2bf(acc[m][n][1]),
                    f2bf(acc[m][n][2]), f2bf(acc[m][n][3])};
        *(u16x4*)&vt[(size_t)(bb * 1024 + hd) * S_LEN + s] = pk;
      }
  } else {
#pragma unroll
    for (int m = 0; m < 4; m++)
#pragma unroll
      for (int n = 0; n < 4; n++)
#pragma unroll
        for (int r = 0; r < 4; r++) {
          int row = rb + m * 16 + r, col = cb + n * 16;
          if (MODE == 1)
            ((u16*)Out)[(size_t)row * 2048 + col] = f2bf(acc[m][n][r]);
          else
            ((float*)Out)[(size_t)row * N + col] = acc[m][n][r];
        }
  }
}

// ---------------- causal flash attention ----------------
// grid: (bh=32, jslot=32). qt remapped so per-CU co-resident work is uniform.
// block 256 = 4 waves; wave w owns q rows [q0+16w, q0+16w+16). KVBLK=64.
__global__ __launch_bounds__(256) void k_attn(const u16* __restrict__ qk,
                                              const u16* __restrict__ vt,
                                              u16* __restrict__ aout) {
  __shared__ u16 Ks[64 * 64];     // K tile [kv][d], XOR-swizzled
  __shared__ u16 Vs[64 * 64];     // V^T tile [d][kv], XOR-swizzled
  __shared__ u16 Ps[4][16 * 64];  // per-wave P [q][kv], XOR-swizzled
  const int tid = threadIdx.x, lane = tid & 63, w = tid >> 6;
  const int l15 = lane & 15, l16 = lane >> 4;
  const int j = blockIdx.y;
  const int qt = (j & 8) ? (j - 8) : (31 - j);  // {c,c+256,c+512,c+768} sums uniform
  const int q0 = qt * 64;
  const int bh = blockIdx.x, b = bh >> 4, h = bh & 15;
  const u16* qbase = qk + (size_t)b * S_LEN * 2048 + h * 64;
  const u16* kbase = qbase + 1024;
  const u16* vbase = vt + (size_t)bh * 64 * S_LEN;
  const int wq0 = q0 + w * 16;

  bf16x8 qa[2];
#pragma unroll
  for (int kb = 0; kb < 2; kb++)
    qa[kb] = *(const bf16x8*)&qbase[(size_t)(wq0 + l15) * 2048 + kb * 32 + l16 * 8];

  f32x4 osum[4] = {};
  float mrow[4], lrow[4];
#pragma unroll
  for (int r = 0; r < 4; r++) { mrow[r] = -1e30f; lrow[r] = 0.f; }

  const int nt = qt + 1;  // 64-wide kv tiles
  const int srow = tid >> 2, scg = (tid & 3) * 16;
  u32x4 kr0, kr1, vr0, vr1;
  {
    const u16* kp = kbase + (size_t)srow * 2048 + scg;
    kr0 = *(const u32x4*)kp; kr1 = *(const u32x4*)(kp + 8);
    const u16* vp = vbase + (size_t)srow * S_LEN + scg;
    vr0 = *(const u32x4*)vp; vr1 = *(const u32x4*)(vp + 8);
  }

  for (int t = 0; t < nt; t++) {
    const int kv0 = t * 64;
    __syncthreads();  // everyone done reading previous tile
    *(u32x4*)&Ks[swz(srow, scg)]     = kr0;
    *(u32x4*)&Ks[swz(srow, scg + 8)] = kr1;
    *(u32x4*)&Vs[swz(srow, scg)]     = vr0;
    *(u32x4*)&Vs[swz(srow, scg + 8)] = vr1;
    __syncthreads();  // tile ready
    if (t + 1 < nt) {  // issue next-tile loads; they drain under compute (T14-lite)
      const u16* kp = kbase + (size_t)(kv0 + 64 + srow) * 2048 + scg;
      kr0 = *(const u32x4*)kp; kr1 = *(const u32x4*)(kp + 8);
      const u16* vp = vbase + (size_t)srow * S_LEN + kv0 + 64 + scg;
      vr0 = *(const u32x4*)vp; vr1 = *(const u32x4*)(vp + 8);
    }

    // QK^T: 32 q x 64 kv per wave? -> 16 q rows x 64 kv (4 n-frags), K in 2 steps
    f32x4 sc[4];
#pragma unroll
    for (int n = 0; n < 4; n++) {
      bf16x8 kf0 = *(const bf16x8*)&Ks[swz(n * 16 + l15, l16 * 8)];
      bf16x8 kf1 = *(const bf16x8*)&Ks[swz(n * 16 + l15, 32 + l16 * 8)];
      f32x4 z = {0.f, 0.f, 0.f, 0.f};
      z = __builtin_amdgcn_mfma_f32_16x16x32_bf16(qa[0], kf0, z, 0, 0, 0);
      sc[n] = __builtin_amdgcn_mfma_f32_16x16x32_bf16(qa[1], kf1, z, 0, 0, 0);
    }

    const bool diag = (t == nt - 1);
#pragma unroll
    for (int r = 0; r < 4; r++) {
      const int qrow = wq0 + l16 * 4 + r;
      float mt = -1e30f;
#pragma unroll
      for (int n = 0; n < 4; n++) {
        float s = sc[n][r] * 0.125f;
        if (diag && (kv0 + n * 16 + l15 > qrow)) s = -1e30f;
        sc[n][r] = s;
        mt = fmaxf(mt, s);
      }
      mt = fmaxf(mt, __shfl_xor(mt, 1));
      mt = fmaxf(mt, __shfl_xor(mt, 2));
      mt = fmaxf(mt, __shfl_xor(mt, 4));
      mt = fmaxf(mt, __shfl_xor(mt, 8));
      float mnew = fmaxf(mrow[r], mt);
      float alpha = __expf(mrow[r] - mnew);
      mrow[r] = mnew;
      float rs = 0.f;
#pragma unroll
      for (int n = 0; n < 4; n++) {
        float p = __expf(sc[n][r] - mnew);
        Ps[w][swz(l16 * 4 + r, n * 16 + l15)] = f2bf(p);
        rs += p;
      }
      rs += __shfl_xor(rs, 1);
      rs += __shfl_xor(rs, 2);
      rs += __shfl_xor(rs, 4);
      rs += __shfl_xor(rs, 8);
      lrow[r] = lrow[r] * alpha + rs;
#pragma unroll
      for (int n = 0; n < 4; n++) osum[n][r] *= alpha;
    }

    // PV: A = P (16q x 64kv), B^T = V^T (d x kv). Same-wave LDS, no barrier.
#pragma unroll
    for (int ks = 0; ks < 2; ks++) {
      bf16x8 pa = *(const bf16x8*)&Ps[w][swz(l15, ks * 32 + l16 * 8)];
#pragma unroll
      for (int n = 0; n < 4; n++) {
        bf16x8 vb = *(const bf16x8*)&Vs[swz(n * 16 + l15, ks * 32 + l16 * 8)];
        osum[n] = __builtin_amdgcn_mfma_f32_16x16x32_bf16(pa, vb, osum[n], 0, 0, 0);
      }
    }
  }

#pragma unroll
  for (int r = 0; r < 4; r++) lrow[r] = 1.f / lrow[r];
  u16* ob = aout + (size_t)b * S_LEN * DMODEL + h * 64;
#pragma unroll
  for (int n = 0; n < 4; n++)
#pragma unroll
    for (int r = 0; r < 4; r++) {
      int s = wq0 + l16 * 4 + r;
      ob[(size_t)s * DMODEL + n * 16 + l15] = f2bf(osum[n][r] * lrow[r]);
    }
}

extern "C" void kernel_launch(void* const* d_in, const int* in_sizes, int n_in,
                              void* d_out, int out_size, void* d_ws, size_t ws_size,
                              hipStream_t stream) {
  const float* x = (const float*)d_in[0];
  const int* pos = (const int*)d_in[1];
  const float* wqkv = (const float*)d_in[2];
  const float* wout = (const float*)d_in[3];
  float* out = (float*)d_out;
  char* ws = (char*)d_ws;

  // workspace layout (bytes) — 50.9 MB total (same as round 1)
  u16* qkb  = (u16*)(ws);                       // [4096][2048] q,k  16,777,216
  u16* vtb  = (u16*)(ws + 16777216);            // [2][16][64][2048]  8,388,608
  u16* aoutb = (u16*)(ws + 25165824);           // [4096][1024]       8,388,608
  u16* xb   = (u16*)(ws + 33554432);            //                    8,388,608
  u16* wqb  = (u16*)(ws + 41943040);            //                    6,291,456
  u16* wob  = (u16*)(ws + 48234496);            //                    2,097,152
  float* ctab = (float*)(ws + 50331648);        //                      262,144
  float* stab = (float*)(ws + 50593792);        //                      262,144
  (void)ws_size;

  k_f32_to_bf16<<<(4194304 / 8) / 256, 256, 0, stream>>>(x, xb, 4194304 / 8);
  k_f32_to_bf16<<<(3145728 / 8) / 256, 256, 0, stream>>>(wqkv, wqb, 3145728 / 8);
  k_f32_to_bf16<<<(1048576 / 8) / 256, 256, 0, stream>>>(wout, wob, 1048576 / 8);
  k_rope_tab<<<65536 / 256, 256, 0, stream>>>(pos, ctab, stab);

  dim3 g1(ROWS / 128, EX / 128);  // 32 x 24
  k_gemm_bt<1><<<g1, 256, 0, stream>>>(xb, wqb, qkb, vtb, ROWS, EX, DMODEL);

  k_rope<<<(ROWS * 1024) / 256, 256, 0, stream>>>(qkb, ctab, stab);

  dim3 ga(2 * NHEAD, S_LEN / 64);  // x = bh (fast), y = qtile slot
  k_attn<<<ga, 256, 0, stream>>>(qkb, vtb, aoutb);

  dim3 g2(ROWS / 128, DMODEL / 128);  // 32 x 8
  k_gemm_bt<0><<<g2, 256, 0, stream>>>(aoutb, wob, out, nullptr, ROWS, DMODEL, DMODEL);
}

// Round 3
// 119.742 us; speedup vs baseline: 2.5182x; 1.3249x over previous
//
#include <hip/hip_runtime.h>

typedef unsigned short u16;
typedef unsigned int u32;
typedef __attribute__((ext_vector_type(8))) __bf16 bf16x8;
typedef __attribute__((ext_vector_type(4))) float f32x4;
typedef __attribute__((ext_vector_type(4))) u32 u32x4;
typedef __attribute__((ext_vector_type(4))) u16 u16x4;

#define DEV __device__ __forceinline__

constexpr int S_LEN = 2048;
constexpr int DMODEL = 1024;
constexpr int NHEAD = 16;
constexpr int EX = 3072;     // 3*D
constexpr int ROWS = 4096;   // B*S
// fold 1/sqrt(64) * log2(e) into Q so softmax is exp2(s - B), B = 16
constexpr float QSCALE = 0.125f * 1.4426950408889634f;

DEV u16 f2bf(float f) {
  union { float f; u32 u; } v; v.f = f;
  u32 u = v.u;
  u32 r = (u + 0x7fffu + ((u >> 16) & 1u)) >> 16;  // RNE
  return (u16)r;
}
DEV float bf2f(u32 lo16) {
  union { u32 u; float f; } v; v.u = lo16 << 16; return v.f;
}
DEV float vexp2(float x) {
#if __has_builtin(__builtin_amdgcn_exp2f)
  return __builtin_amdgcn_exp2f(x);
#else
  return exp2f(x);
#endif
}
// async global->LDS, 16B per lane (m97 recipe)
DEV void gload_lds16(const u16* g, u16* l) {
  __builtin_amdgcn_global_load_lds((const __attribute__((address_space(1))) void*)g,
                                   (__attribute__((address_space(3))) void*)l, 16, 0, 0);
}
// XOR swizzle for [rows][64] u16 LDS tiles (row stride 128B), 8-col granules
DEV int swz(int r, int c) { return r * 64 + (c ^ ((r & 7) << 3)); }

// ---------------- fused fp32 -> bf16 convert for x, w_qkv, w_out ----------------
__global__ __launch_bounds__(256) void k_cvt_all(const float* __restrict__ x,
                                                 const float* __restrict__ wq,
                                                 const float* __restrict__ wo,
                                                 u16* __restrict__ xb,
                                                 u16* __restrict__ wqb,
                                                 u16* __restrict__ wob) {
  int i = blockIdx.x * 256 + threadIdx.x;  // 1048576 total (x8 elems)
  const float* in; u16* out; int off;
  if (i < 524288)       { in = x;  out = xb;  off = i; }
  else if (i < 917504)  { in = wq; out = wqb; off = i - 524288; }
  else                  { in = wo; out = wob; off = i - 917504; }
  const float4* p4 = (const float4*)in;
  float4 a = p4[2 * off], b = p4[2 * off + 1];
  alignas(16) u16 r[8] = {f2bf(a.x), f2bf(a.y), f2bf(a.z), f2bf(a.w),
                          f2bf(b.x), f2bf(b.y), f2bf(b.z), f2bf(b.w)};
  *(u32x4*)(out + 8 * off) = *(const u32x4*)r;
}

// ---------------- RoPE cos/sin tables: [S][32] ----------------
__global__ __launch_bounds__(256) void k_rope_tab(const int* __restrict__ pos,
                                                  float* __restrict__ ctab,
                                                  float* __restrict__ stab) {
  int t = blockIdx.x * 256 + threadIdx.x;  // S*32 = 65536
  int s = t >> 5, fi = t & 31;
  float p = (float)pos[s];
  float invf = expf(-(float)fi * 0.28782313662425572f);  // 10000^(-fi/32)
  float ang = p * invf;
  ctab[t] = cosf(ang);
  stab[t] = sinf(ang);
}

// ---------------- in-place RoPE on qk buffer [ROWS][2048] (bf16) ----------------
// q third (p==0) additionally scaled by QSCALE for exp2-softmax
__global__ __launch_bounds__(256) void k_rope(u16* __restrict__ qk,
                                              const float* __restrict__ ctab,
                                              const float* __restrict__ stab) {
  int idx = blockIdx.x * 256 + threadIdx.x;  // ROWS * 1024 pair-slots
  int row = idx >> 10, rem = idx & 1023;
  int p = rem >> 9, hfi = rem & 511;
  int h = hfi >> 5, fi = hfi & 31;
  int s = row & (S_LEN - 1);
  u32* ptr = (u32*)(qk + (size_t)row * 2048 + p * 1024 + h * 64 + 2 * fi);
  u32 v = *ptr;
  float xe = bf2f(v & 0xffffu), xo = bf2f(v >> 16);
  float c = ctab[s * 32 + fi], sn = stab[s * 32 + fi];
  float scl = (p == 0) ? QSCALE : 1.0f;
  u32 lo = (u32)f2bf((xe * c - xo * sn) * scl);
  u32 hi = (u32)f2bf((xe * sn + xo * c) * scl);
  *ptr = lo | (hi << 16);
}

// ---------------- GEMM: C[m][n] = sum_k A[m][k] * B[n][k]  (bf16, B^T layout)
// m97 structure: 128x128 tile, BK=32, global_load_lds(16B) -> linear LDS.
// MODE 0: fp32 out [M][N].  MODE 1: qkv split — cols<2048 -> bf16 qk[row][2048];
// cols>=2048 (V third) -> transposed bf16 vt[(b*16+h)*64+d][s].
template <int MODE>
__global__ __launch_bounds__(256) void k_gemm_bt(const u16* __restrict__ A,
                                                 const u16* __restrict__ Bw,
                                                 void* __restrict__ Out,
                                                 u16* __restrict__ vt,
                                                 int M, int N, int K) {
  __shared__ alignas(16) u16 As[128 * 32];
  __shared__ alignas(16) u16 Bs[128 * 32];
  const int tid = threadIdx.x, lane = tid & 63;
  const int w = tid >> 6, wr = w >> 1, wc = w & 1;
  const int l15 = lane & 15, l16 = lane >> 4;
  const int m0 = blockIdx.x * 128, n0 = blockIdx.y * 128;
  f32x4 acc[4][4] = {};
  // wave w, issue i covers LDS bytes [w*2048 + i*1024, +1024): row-major [128][32]
  const int grow = w * 32 + (lane >> 2);      // + i*16
  const int gcol = (lane & 3) * 8;
  const int ldst = w * 1024 + lane * 8;       // u16 index; + i*512

  for (int k0 = 0; k0 < K; k0 += 32) {
    __syncthreads();
#pragma unroll
    for (int i = 0; i < 2; i++) {
      gload_lds16(&A[(size_t)(m0 + grow + i * 16) * K + k0 + gcol], &As[ldst + i * 512]);
      gload_lds16(&Bw[(size_t)(n0 + grow + i * 16) * K + k0 + gcol], &Bs[ldst + i * 512]);
    }
    __syncthreads();
    bf16x8 af[4], bfr[4];
#pragma unroll
    for (int m = 0; m < 4; m++) af[m] = *(const bf16x8*)&As[(wr * 64 + m * 16 + l15) * 32 + l16 * 8];
#pragma unroll
    for (int n = 0; n < 4; n++) bfr[n] = *(const bf16x8*)&Bs[(wc * 64 + n * 16 + l15) * 32 + l16 * 8];
#pragma unroll
    for (int m = 0; m < 4; m++)
#pragma unroll
      for (int n = 0; n < 4; n++)
        acc[m][n] = __builtin_amdgcn_mfma_f32_16x16x32_bf16(af[m], bfr[n], acc[m][n], 0, 0, 0);
  }

  // C/D layout (m89/m91): col = lane&15, row = (lane>>4)*4 + reg
  const int rb = m0 + wr * 64 + l16 * 4;
  const int cb = n0 + wc * 64 + l15;
  if (MODE == 1 && n0 >= 2048) {
#pragma unroll
    for (int m = 0; m < 4; m++)
#pragma unroll
      for (int n = 0; n < 4; n++) {
        int row = rb + m * 16;            // 4 consecutive rows r=0..3
        int col = cb + n * 16;
        int bb = row >> 11, s = row & 2047, hd = col - 2048;
        u16x4 pk = {f2bf(acc[m][n][0]), f2bf(acc[m][n][1]),
                    f2bf(acc[m][n][2]), f2bf(acc[m][n][3])};
        *(u16x4*)&vt[(size_t)(bb * 1024 + hd) * S_LEN + s] = pk;
      }
  } else {
#pragma unroll
    for (int m = 0; m < 4; m++)
#pragma unroll
      for (int n = 0; n < 4; n++)
#pragma unroll
        for (int r = 0; r < 4; r++) {
          int row = rb + m * 16 + r, col = cb + n * 16;
          if (MODE == 1)
            ((u16*)Out)[(size_t)row * 2048 + col] = f2bf(acc[m][n][r]);
          else
            ((float*)Out)[(size_t)row * N + col] = acc[m][n][r];
        }
  }
}

// ---------------- causal flash attention, fixed-max exp2 softmax ----------------
// grid: (bh=32, j=32), qt = 31-j (LPT: long blocks first). 4 waves, wave w owns
// q rows [q0+16w, q0+16w+16). KVBLK=64. lsum via MFMA-with-ones.
__global__ __launch_bounds__(256) void k_attn(const u16* __restrict__ qk,
                                              const u16* __restrict__ vt,
                                              u16* __restrict__ aout) {
  __shared__ alignas(16) u16 Ks[64 * 64];     // K tile [kv][d], swizzled
  __shared__ alignas(16) u16 Vs[64 * 64];     // V^T tile [d][kv], swizzled
  __shared__ alignas(16) u16 Ps[4][16 * 64];  // per-wave P [q][kv], swizzled
  const int tid = threadIdx.x, lane = tid & 63, w = tid >> 6;
  const int l15 = lane & 15, l16 = lane >> 4;
  const int qt = 31 - blockIdx.y;
  const int q0 = qt * 64;
  const int bh = blockIdx.x, b = bh >> 4, h = bh & 15;
  const u16* qbase = qk + (size_t)b * S_LEN * 2048 + h * 64;
  const u16* kbase = qbase + 1024;
  const u16* vbase = vt + (size_t)bh * 64 * S_LEN;
  const int wq0 = q0 + w * 16;

  bf16x8 qa[2];
#pragma unroll
  for (int kb = 0; kb < 2; kb++)
    qa[kb] = *(const bf16x8*)&qbase[(size_t)(wq0 + l15) * 2048 + kb * 32 + l16 * 8];

  bf16x8 vone;
#pragma unroll
  for (int j = 0; j < 8; j++) vone[j] = (__bf16)1.0f;

  f32x4 osum[4] = {};
  f32x4 osl = {};  // row-sum of P (all 16 cols identical)

  const int nt = qt + 1;  // 64-wide kv tiles
  const int srow = tid >> 2, scg = (tid & 3) * 16;
  u32x4 kr0, kr1, vr0, vr1;
  {
    const u16* kp = kbase + (size_t)srow * 2048 + scg;
    kr0 = *(const u32x4*)kp; kr1 = *(const u32x4*)(kp + 8);
    const u16* vp = vbase + (size_t)srow * S_LEN + scg;
    vr0 = *(const u32x4*)vp; vr1 = *(const u32x4*)(vp + 8);
  }

  for (int t = 0; t < nt; t++) {
    const int kv0 = t * 64;
    __syncthreads();  // everyone done reading previous tile
    *(u32x4*)&Ks[swz(srow, scg)]     = kr0;
    *(u32x4*)&Ks[swz(srow, scg + 8)] = kr1;
    *(u32x4*)&Vs[swz(srow, scg)]     = vr0;
    *(u32x4*)&Vs[swz(srow, scg + 8)] = vr1;
    __syncthreads();  // tile ready
    if (t + 1 < nt) {  // register prefetch of next tile drains under compute
      const u16* kp = kbase + (size_t)(kv0 + 64 + srow) * 2048 + scg;
      kr0 = *(const u32x4*)kp; kr1 = *(const u32x4*)(kp + 8);
      const u16* vp = vbase + (size_t)srow * S_LEN + kv0 + 64 + scg;
      vr0 = *(const u32x4*)vp; vr1 = *(const u32x4*)(vp + 8);
    }

    // QK^T: 16 q rows x 64 kv per wave (Q pre-scaled by QSCALE)
    f32x4 sc[4];
#pragma unroll
    for (int n = 0; n < 4; n++) {
      bf16x8 kf0 = *(const bf16x8*)&Ks[swz(n * 16 + l15, l16 * 8)];
      bf16x8 kf1 = *(const bf16x8*)&Ks[swz(n * 16 + l15, 32 + l16 * 8)];
      f32x4 z = {0.f, 0.f, 0.f, 0.f};
      z = __builtin_amdgcn_mfma_f32_16x16x32_bf16(qa[0], kf0, z, 0, 0, 0);
      sc[n] = __builtin_amdgcn_mfma_f32_16x16x32_bf16(qa[1], kf1, z, 0, 0, 0);
    }

    // P = exp2(s - 16); causal mask only on the diagonal tile
    const bool diag = (t == nt - 1);
#pragma unroll
    for (int n = 0; n < 4; n++)
#pragma unroll
      for (int r = 0; r < 4; r++) {
        float s = sc[n][r];
        if (diag && (kv0 + n * 16 + l15 > wq0 + l16 * 4 + r)) s = -1e30f;
        float p = vexp2(s - 16.0f);
        Ps[w][swz(l16 * 4 + r, n * 16 + l15)] = f2bf(p);
      }

    // PV + row-sum: A = P (16q x 64kv), B^T = V^T. Same-wave LDS, no barrier.
#pragma unroll
    for (int ks = 0; ks < 2; ks++) {
      bf16x8 pa = *(const bf16x8*)&Ps[w][swz(l15, ks * 32 + l16 * 8)];
      osl = __builtin_amdgcn_mfma_f32_16x16x32_bf16(pa, vone, osl, 0, 0, 0);
#pragma unroll
      for (int n = 0; n < 4; n++) {
        bf16x8 vb = *(const bf16x8*)&Vs[swz(n * 16 + l15, ks * 32 + l16 * 8)];
        osum[n] = __builtin_amdgcn_mfma_f32_16x16x32_bf16(pa, vb, osum[n], 0, 0, 0);
      }
    }
  }

  f32x4 inv;
#pragma unroll
  for (int r = 0; r < 4; r++) inv[r] = 1.0f / osl[r];
  u16* ob = aout + (size_t)b * S_LEN * DMODEL + h * 64;
#pragma unroll
  for (int n = 0; n < 4; n++)
#pragma unroll
    for (int r = 0; r < 4; r++) {
      int s = wq0 + l16 * 4 + r;
      ob[(size_t)s * DMODEL + n * 16 + l15] = f2bf(osum[n][r] * inv[r]);
    }
}

extern "C" void kernel_launch(void* const* d_in, const int* in_sizes, int n_in,
                              void* d_out, int out_size, void* d_ws, size_t ws_size,
                              hipStream_t stream) {
  const float* x = (const float*)d_in[0];
  const int* pos = (const int*)d_in[1];
  const float* wqkv = (const float*)d_in[2];
  const float* wout = (const float*)d_in[3];
  float* out = (float*)d_out;
  char* ws = (char*)d_ws;

  // workspace layout (bytes) — ~50.9 MB total
  u16* qkb  = (u16*)(ws);                       // [4096][2048] q,k  16,777,216
  u16* vtb  = (u16*)(ws + 16777216);            // [2][16][64][2048]  8,388,608
  u16* aoutb = (u16*)(ws + 25165824);           // [4096][1024]       8,388,608
  u16* xb   = (u16*)(ws + 33554432);            //                    8,388,608
  u16* wqb  = (u16*)(ws + 41943040);            //                    6,291,456
  u16* wob  = (u16*)(ws + 48234496);            //                    2,097,152
  float* ctab = (float*)(ws + 50331648);        //                      262,144
  float* stab = (float*)(ws + 50593792);        //                      262,144
  (void)ws_size;

  k_cvt_all<<<4096, 256, 0, stream>>>(x, wqkv, wout, xb, wqb, wob);
  k_rope_tab<<<65536 / 256, 256, 0, stream>>>(pos, ctab, stab);

  dim3 g1(ROWS / 128, EX / 128);  // 32 x 24
  k_gemm_bt<1><<<g1, 256, 0, stream>>>(xb, wqb, qkb, vtb, ROWS, EX, DMODEL);

  k_rope<<<(ROWS * 1024) / 256, 256, 0, stream>>>(qkb, ctab, stab);

  dim3 ga(2 * NHEAD, S_LEN / 64);  // x = bh (fast, XCD spread), y = qtile slot
  k_attn<<<ga, 256, 0, stream>>>(qkb, vtb, aoutb);

  dim3 g2(ROWS / 128, DMODEL / 128);  // 32 x 8
  k_gemm_bt<0><<<g2, 256, 0, stream>>>(aoutb, wob, out, nullptr, ROWS, DMODEL, DMODEL);
}